// Round 18
// baseline (64.374 us; speedup 1.0000x reference)
//
#include <hip/hip_runtime.h>

#define CROP 14
#define NPOS (CROP * CROP)       // 196
#define CHANNELS 256
#define BATCH 2
#define CPB 16                   // channels per block (16 blocks per proposal)
#define NBLK (CHANNELS / CPB)    // 16
#define WIN_FLOATS 4096          // 16 KiB window buffer (+3.9 KB tables -> 8 blocks/CU)
#define SLOT_MAX_P 512           // padded-slot fallback threshold
#define NQUAD 49
#define NSUB 5                   // 5*49 = 245 active sample threads

typedef float __attribute__((ext_vector_type(4))) fx4;

// Block = (proposal, 16-channel slice).
// 1) issue async global_load_lds (width 16: lane covers a 4-float row chunk;
//    LDS row stride padded to WWP=4*cpr so dest = uniform + lane*16)
// 2) WHILE loads fly: tid<196 computes its position's bilinear entry into LDS
// 3) one __syncthreads drain; 4) sample quads + dwordx4 stores.
__global__ __launch_bounds__(256) void crop_roi_kernel(
    const float* __restrict__ p2, const float* __restrict__ p3,
    const float* __restrict__ p4, const float* __restrict__ p5,
    const float* __restrict__ props, float* __restrict__ out)
{
    const int blk   = blockIdx.x;
    const int n     = blk >> 4;            // proposal
    const int chunk = blk & 15;            // 16-channel slice
    const int tid   = threadIdx.x;
    const int lane  = tid & 63;
    const int wid   = tid >> 6;

    __shared__ float win[WIN_FLOATS];
    __shared__ fx4   wtab[NPOS];           // packed weights per position
    __shared__ int   atab[NPOS];           // slot-local corner address

    // ---- proposal setup (uniform across block; computed redundantly) ----
    const int   bimg = (int)props[n * 7 + 0];
    const float bx0  = props[n * 7 + 1];
    const float by0  = props[n * 7 + 2];
    const float bx1  = props[n * 7 + 3];
    const float by1  = props[n * 7 + 4];

    const float sz = sqrtf((bx1 - bx0) * (by1 - by0));
    int lvl = 0; float bd = fabsf(sz - 8.0f), d;
    d = fabsf(sz - 16.0f); if (d < bd) { bd = d; lvl = 1; }
    d = fabsf(sz - 32.0f); if (d < bd) { bd = d; lvl = 2; }
    d = fabsf(sz - 64.0f); if (d < bd) { bd = d; lvl = 3; }

    const int   H     = 256 >> lvl;                 // H == W (multiple of 4)
    const int   HW    = H * H;
    const float scale = 0.25f / (float)(1 << lvl);  // exact
    const float* fp   = (lvl == 0) ? p2 : (lvl == 1) ? p3 : (lvl == 2) ? p4 : p5;
    const float* base = fp + (size_t)bimg * CHANNELS * HW
                           + (size_t)(chunk * CPB) * HW;

    // ---- window bounds (uniform) ----
    const float xs0 = bx0 * scale, xs1 = bx1 * scale;
    const float ys0 = by0 * scale, ys1 = by1 * scale;
    const int x_lo = min((int)floorf(xs0), H - 2);
    const int x_hi = min((int)floorf(xs1), H - 2) + 1;
    const int y_lo = min((int)floorf(ys0), H - 2);
    const int y_hi = min((int)floorf(ys1), H - 2) + 1;
    const int x_al = x_lo & ~3;            // 16B-aligned window start
    const int WWal = x_hi - x_al + 1;      // cols staged (pre-pad)
    const int WH   = y_hi - y_lo + 1;
    const int cpr  = (WWal + 3) >> 2;      // 16B chunks per row
    const int WWP  = cpr << 2;             // padded LDS row stride (floats)
    const int SLOTP = WH * WWP;            // padded floats per channel slot

    float* __restrict__ outp = out + ((size_t)n * CHANNELS + chunk * CPB) * NPOS;

    if (SLOTP <= SLOT_MAX_P) {
        // width-16 is unsafe only for the block staging the buffer's very
        // last channel (pad cols could read past the allocation end).
        const bool use16 = !(bimg == BATCH - 1 && chunk == NBLK - 1);

        // ---- staging lane geometry (one-time) ----
        // 16B path: lane -> (row-in-pass, 4-float chunk)
        const int  rpp  = 64 / cpr;
        const int  rin6 = lane / cpr;
        const int  ch6  = (lane - rin6 * cpr) << 2;   // col offset (floats)
        const bool ok6  = (lane < rpp * cpr);
        // 4B masked path (rare): lane -> (row-in-pass, col) at WWP stride
        const int  rpw  = 64 / WWP;
        const int  rin4 = lane / WWP;
        const int  col4 = lane - rin4 * WWP;
        const bool ok4  = (lane < rpw * WWP) && (col4 < WWal);

        int CG = WIN_FLOATS / SLOTP; if (CG > CPB) CG = CPB;  // >= 8 always

        auto stageGroup = [&](int g0, int gn) {
            if (use16) {
                for (int c = wid; c < gn; c += 4) {
                    const float* __restrict__ f = base + (size_t)(g0 + c) * HW
                                                       + (size_t)y_lo * H + x_al;
                    for (int p = 0; p * rpp < WH; ++p) {
                        const int row = p * rpp + rin6;
                        if (ok6 && row < WH) {
                            __builtin_amdgcn_global_load_lds(
                                (const __attribute__((address_space(1))) void*)(f + row * H + ch6),
                                (__attribute__((address_space(3))) void*)&win[c * SLOTP + p * rpp * WWP],
                                16, 0, 0);
                        }
                    }
                }
            } else {
                for (int c = wid; c < gn; c += 4) {
                    const float* __restrict__ f = base + (size_t)(g0 + c) * HW
                                                       + (size_t)y_lo * H + x_al;
                    for (int p = 0; p * rpw < WH; ++p) {
                        const int row = p * rpw + rin4;
                        if (ok4 && row < WH) {
                            __builtin_amdgcn_global_load_lds(
                                (const __attribute__((address_space(1))) void*)(f + row * H + col4),
                                (__attribute__((address_space(3))) void*)&win[c * SLOTP + p * rpw * WWP],
                                4, 0, 0);
                        }
                    }
                }
            }
        };

        // ---- ISSUE stage loads for group 0 FIRST (async -> LDS) ----
        stageGroup(0, min(CG, CPB));

        // ---- build the per-position table WHILE loads are in flight ----
        if (tid < NPOS) {
            const int py = tid / CROP;
            const int px = tid - py * CROP;

            const float gy  = (float)py / 13.0f;
            const float ysv = ys0 + (ys1 - ys0) * gy;
            const float yfv = floorf(ysv);
            const float ly  = ysv - yfv;                  // unclamped (ref)
            const int   yi0 = min((int)yfv, H - 1);       // ysv >= 0
            const bool  ycl = (yi0 == H - 1);
            const int   byl = (ycl ? H - 2 : yi0) - y_lo;
            const float wy0 = ycl ? 0.0f : 1.0f - ly;
            const float wy1 = ycl ? 1.0f : ly;

            const float gx  = (float)px / 13.0f;
            const float xsv = xs0 + (xs1 - xs0) * gx;
            const float xfv = floorf(xsv);
            const float lx  = xsv - xfv;
            const int   xi0 = min((int)xfv, H - 1);
            const bool  xcl = (xi0 == H - 1);
            const int   bxl = (xcl ? H - 2 : xi0) - x_al;
            const float wx0 = xcl ? 0.0f : 1.0f - lx;
            const float wx1 = xcl ? 1.0f : lx;

            fx4 w;
            w.x = wy0 * wx0;   // w00
            w.y = wy0 * wx1;   // w01
            w.z = wy1 * wx0;   // w10
            w.w = wy1 * wx1;   // w11
            wtab[tid] = w;
            atab[tid] = byl * WWP + bxl;
        }

        const int q   = tid % NQUAD;       // quad index (pos 4q..4q+3)
        const int sub = tid / NQUAD;       // channel substream 0..4 (5=idle)
        const bool smp = (sub < NSUB);
        float* __restrict__ opq = outp + 4 * q;

        bool have_params = false;
        fx4 wj[4]; int a0[4];

        for (int g0 = 0; g0 < CPB; g0 += CG) {
            const int gn = min(CG, CPB - g0);

            if (g0) {
                __syncthreads();           // rare 2nd group: protect reads
                stageGroup(g0, gn);
            }
            __syncthreads();               // drain: windows + table resident

            if (smp) {
                if (!have_params) {        // one-time table read (post-barrier)
                    #pragma unroll
                    for (int j = 0; j < 4; ++j) {
                        wj[j] = wtab[4 * q + j];
                        a0[j] = atab[4 * q + j];
                    }
                    have_params = true;
                }
                for (int c = sub; c < gn; c += NSUB) {
                    const int sb = c * SLOTP;
                    fx4 r;
                    #pragma unroll
                    for (int j = 0; j < 4; ++j) {
                        const int a = sb + a0[j];
                        const float v00 = win[a];
                        const float v01 = win[a + 1];        // ds_read2 pair
                        const float v10 = win[a + WWP];
                        const float v11 = win[a + WWP + 1];  // ds_read2 pair
                        r[j] = v00 * wj[j].x + v01 * wj[j].y
                             + v10 * wj[j].z + v11 * wj[j].w;
                    }
                    *reinterpret_cast<fx4*>(opq + (size_t)(g0 + c) * NPOS) = r;
                }
            }
        }
    } else {
        // ================= direct fallback (safety; not expected) ==========
        if (tid < NPOS) {
            const int pos = tid;
            const int py  = pos / CROP;
            const int px  = pos - py * CROP;

            const float gy  = (float)py / 13.0f;
            const float ysv = ys0 + (ys1 - ys0) * gy;
            const float yfv = floorf(ysv);
            const float ly  = ysv - yfv;
            const int   yi0 = min((int)yfv, H - 1);
            const float gx  = (float)px / 13.0f;
            const float xsv = xs0 + (xs1 - xs0) * gx;
            const float xfv = floorf(xsv);
            const float lx  = xsv - xfv;
            const int   xi0 = min((int)xfv, H - 1);

            const int yi1 = min(yi0 + 1, H - 1);
            const int xi1 = min(xi0 + 1, H - 1);
            const int o00 = yi0 * H + xi0;
            const int o01 = yi0 * H + xi1;
            const int o10 = yi1 * H + xi0;
            const int o11 = yi1 * H + xi1;
            const float omy = 1.0f - ly, omx = 1.0f - lx;
            const float w00 = omy * omx, w01 = omy * lx;
            const float w10 = ly * omx,  w11 = ly * lx;

            #pragma unroll 4
            for (int c = 0; c < CPB; ++c) {
                const float* __restrict__ f = base + (size_t)c * HW;
                const float v = f[o00] * w00 + f[o01] * w01
                              + f[o10] * w10 + f[o11] * w11;
                outp[(size_t)c * NPOS + pos] = v;
            }
        }
    }
}

extern "C" void kernel_launch(void* const* d_in, const int* in_sizes, int n_in,
                              void* d_out, int out_size, void* d_ws, size_t ws_size,
                              hipStream_t stream) {
    const float* p2    = (const float*)d_in[0];
    const float* p3    = (const float*)d_in[1];
    const float* p4    = (const float*)d_in[2];
    const float* p5    = (const float*)d_in[3];
    const float* props = (const float*)d_in[4];
    float* outp        = (float*)d_out;

    const int N = in_sizes[4] / 7;          // 1024 proposals
    dim3 grid(N * NBLK);                    // 16384 blocks
    dim3 block(256);
    hipLaunchKernelGGL(crop_roi_kernel, grid, block, 0, stream,
                       p2, p3, p4, p5, props, outp);
}

// Round 19
// 60.426 us; speedup vs baseline: 1.0653x; 1.0653x over previous
//
#include <hip/hip_runtime.h>

#define CROP 14
#define NPOS (CROP * CROP)       // 196
#define CHANNELS 256
#define CPB 16                   // channels per block (16 blocks per proposal)
#define NBLK (CHANNELS / CPB)    // 16
#define WIN_FLOATS 4096          // 16 KiB window buffer (+3.9 KB tables = 20.3 KB -> 8 blocks/CU)
#define SLOT_MAX 392             // fallback threshold (geometry keeps SLOT <= ~340)
#define NQUAD 49
#define NSUB 5                   // 5*49 = 245 active sample threads

typedef float __attribute__((ext_vector_type(4))) fx4;

// Block = (proposal, 16-channel slice).   [R17 structure, WIN 3584->4096]
// 1) issue async global_load_lds for the ROI windows
// 2) WHILE loads fly: tid<196 each computes ONE position's bilinear entry
//    (addr + 4 premultiplied weights) into an LDS table
// 3) one __syncthreads drain (covers stage loads AND table writes)
// 4) sample: read 4 table entries, 8 ds_read2 + 16 FMA + dwordx4 store/channel
__global__ __launch_bounds__(256) void crop_roi_kernel(
    const float* __restrict__ p2, const float* __restrict__ p3,
    const float* __restrict__ p4, const float* __restrict__ p5,
    const float* __restrict__ props, float* __restrict__ out)
{
    const int blk   = blockIdx.x;
    const int n     = blk >> 4;            // proposal
    const int chunk = blk & 15;            // 16-channel slice
    const int tid   = threadIdx.x;
    const int lane  = tid & 63;
    const int wid   = tid >> 6;

    __shared__ float win[WIN_FLOATS];
    __shared__ fx4   wtab[NPOS];           // packed weights per position
    __shared__ int   atab[NPOS];           // slot-local corner address

    // ---- proposal setup (uniform across block; computed redundantly) ----
    const int   bimg = (int)props[n * 7 + 0];
    const float bx0  = props[n * 7 + 1];
    const float by0  = props[n * 7 + 2];
    const float bx1  = props[n * 7 + 3];
    const float by1  = props[n * 7 + 4];

    const float sz = sqrtf((bx1 - bx0) * (by1 - by0));
    int lvl = 0; float bd = fabsf(sz - 8.0f), d;
    d = fabsf(sz - 16.0f); if (d < bd) { bd = d; lvl = 1; }
    d = fabsf(sz - 32.0f); if (d < bd) { bd = d; lvl = 2; }
    d = fabsf(sz - 64.0f); if (d < bd) { bd = d; lvl = 3; }

    const int   H     = 256 >> lvl;                 // H == W
    const int   HW    = H * H;
    const float scale = 0.25f / (float)(1 << lvl);  // exact
    const float* fp   = (lvl == 0) ? p2 : (lvl == 1) ? p3 : (lvl == 2) ? p4 : p5;
    const float* base = fp + (size_t)bimg * CHANNELS * HW
                           + (size_t)(chunk * CPB) * HW;

    // ---- window bounds (uniform) ----
    const float xs0 = bx0 * scale, xs1 = bx1 * scale;
    const float ys0 = by0 * scale, ys1 = by1 * scale;
    const int x_lo = min((int)floorf(xs0), H - 2);
    const int x_hi = min((int)floorf(xs1), H - 2) + 1;
    const int y_lo = min((int)floorf(ys0), H - 2);
    const int y_hi = min((int)floorf(ys1), H - 2) + 1;
    const int WW = x_hi - x_lo + 1;
    const int WH = y_hi - y_lo + 1;
    const int SLOT = WH * WW;              // floats per channel window

    float* __restrict__ outp = out + ((size_t)n * CHANNELS + chunk * CPB) * NPOS;

    if (SLOT <= SLOT_MAX) {
        // ---- staging lane geometry ----
        const int  wyo  = lane / WW;
        const int  wxl  = lane - wyo * WW;
        const int  kR   = 64 / WW;           // full rows per pass (>=2)
        const int  kRWW = kR * WW;
        const bool wok  = (lane < kRWW);

        int CG = WIN_FLOATS / SLOT; if (CG > CPB) CG = CPB;  // >= 12 always
        const int gn0 = min(CG, CPB);

        // ---- ISSUE stage loads for group 0 FIRST (async -> LDS) ----
        for (int c = wid; c < gn0; c += 4) {
            const float* __restrict__ f = base + (size_t)c * HW
                                               + (size_t)y_lo * H + x_lo;
            for (int p = 0; p * kR < WH; ++p) {
                const int row = p * kR + wyo;
                if (wok && row < WH) {
                    __builtin_amdgcn_global_load_lds(
                        (const __attribute__((address_space(1))) void*)(f + row * H + wxl),
                        (__attribute__((address_space(3))) void*)&win[c * SLOT + p * kRWW],
                        4, 0, 0);
                }
            }
        }

        // ---- build the per-position table WHILE loads are in flight ----
        if (tid < NPOS) {
            const int py = tid / CROP;
            const int px = tid - py * CROP;

            const float gy  = (float)py / 13.0f;
            const float ysv = ys0 + (ys1 - ys0) * gy;
            const float yfv = floorf(ysv);
            const float ly  = ysv - yfv;                  // unclamped (ref)
            const int   yi0 = min((int)yfv, H - 1);       // ysv >= 0
            const bool  ycl = (yi0 == H - 1);
            const int   byl = (ycl ? H - 2 : yi0) - y_lo;
            const float wy0 = ycl ? 0.0f : 1.0f - ly;
            const float wy1 = ycl ? 1.0f : ly;

            const float gx  = (float)px / 13.0f;
            const float xsv = xs0 + (xs1 - xs0) * gx;
            const float xfv = floorf(xsv);
            const float lx  = xsv - xfv;
            const int   xi0 = min((int)xfv, H - 1);
            const bool  xcl = (xi0 == H - 1);
            const int   bxl = (xcl ? H - 2 : xi0) - x_lo;
            const float wx0 = xcl ? 0.0f : 1.0f - lx;
            const float wx1 = xcl ? 1.0f : lx;

            fx4 w;
            w.x = wy0 * wx0;   // w00
            w.y = wy0 * wx1;   // w01
            w.z = wy1 * wx0;   // w10
            w.w = wy1 * wx1;   // w11
            wtab[tid] = w;
            atab[tid] = byl * WW + bxl;
        }

        const int q   = tid % NQUAD;       // quad index (pos 4q..4q+3)
        const int sub = tid / NQUAD;       // channel substream 0..4 (5=idle)
        const bool smp = (sub < NSUB);
        float* __restrict__ opq = outp + 4 * q;

        // ---- group loop (group 0's loads already issued above) ----
        bool have_params = false;
        fx4 wj[4]; int a0[4];

        for (int g0 = 0; g0 < CPB; g0 += CG) {
            const int gn = min(CG, CPB - g0);

            if (g0) {
                __syncthreads();           // rare 2nd group: protect reads
                for (int c = wid; c < gn; c += 4) {
                    const float* __restrict__ f = base + (size_t)(g0 + c) * HW
                                                       + (size_t)y_lo * H + x_lo;
                    for (int p = 0; p * kR < WH; ++p) {
                        const int row = p * kR + wyo;
                        if (wok && row < WH) {
                            __builtin_amdgcn_global_load_lds(
                                (const __attribute__((address_space(1))) void*)(f + row * H + wxl),
                                (__attribute__((address_space(3))) void*)&win[c * SLOT + p * kRWW],
                                4, 0, 0);
                        }
                    }
                }
            }
            __syncthreads();               // drain: windows + table resident

            if (smp) {
                if (!have_params) {        // one-time table read (post-barrier)
                    #pragma unroll
                    for (int j = 0; j < 4; ++j) {
                        wj[j] = wtab[4 * q + j];
                        a0[j] = atab[4 * q + j];
                    }
                    have_params = true;
                }
                for (int c = sub; c < gn; c += NSUB) {
                    const int sb = c * SLOT;
                    fx4 r;
                    #pragma unroll
                    for (int j = 0; j < 4; ++j) {
                        const int a = sb + a0[j];
                        const float v00 = win[a];
                        const float v01 = win[a + 1];       // ds_read2 pair
                        const float v10 = win[a + WW];
                        const float v11 = win[a + WW + 1];  // ds_read2 pair
                        r[j] = v00 * wj[j].x + v01 * wj[j].y
                             + v10 * wj[j].z + v11 * wj[j].w;
                    }
                    *reinterpret_cast<fx4*>(opq + (size_t)(g0 + c) * NPOS) = r;
                }
            }
        }
    } else {
        // ================= direct fallback (safety; not expected) ==========
        if (tid < NPOS) {
            const int pos = tid;
            const int py  = pos / CROP;
            const int px  = pos - py * CROP;

            const float gy  = (float)py / 13.0f;
            const float ysv = ys0 + (ys1 - ys0) * gy;
            const float yfv = floorf(ysv);
            const float ly  = ysv - yfv;
            const int   yi0 = min((int)yfv, H - 1);
            const float gx  = (float)px / 13.0f;
            const float xsv = xs0 + (xs1 - xs0) * gx;
            const float xfv = floorf(xsv);
            const float lx  = xsv - xfv;
            const int   xi0 = min((int)xfv, H - 1);

            const int yi1 = min(yi0 + 1, H - 1);
            const int xi1 = min(xi0 + 1, H - 1);
            const int o00 = yi0 * H + xi0;
            const int o01 = yi0 * H + xi1;
            const int o10 = yi1 * H + xi0;
            const int o11 = yi1 * H + xi1;
            const float omy = 1.0f - ly, omx = 1.0f - lx;
            const float w00 = omy * omx, w01 = omy * lx;
            const float w10 = ly * omx,  w11 = ly * lx;

            #pragma unroll 4
            for (int c = 0; c < CPB; ++c) {
                const float* __restrict__ f = base + (size_t)c * HW;
                const float v = f[o00] * w00 + f[o01] * w01
                              + f[o10] * w10 + f[o11] * w11;
                outp[(size_t)c * NPOS + pos] = v;
            }
        }
    }
}

extern "C" void kernel_launch(void* const* d_in, const int* in_sizes, int n_in,
                              void* d_out, int out_size, void* d_ws, size_t ws_size,
                              hipStream_t stream) {
    const float* p2    = (const float*)d_in[0];
    const float* p3    = (const float*)d_in[1];
    const float* p4    = (const float*)d_in[2];
    const float* p5    = (const float*)d_in[3];
    const float* props = (const float*)d_in[4];
    float* outp        = (float*)d_out;

    const int N = in_sizes[4] / 7;          // 1024 proposals
    dim3 grid(N * NBLK);                    // 16384 blocks
    dim3 block(256);
    hipLaunchKernelGGL(crop_roi_kernel, grid, block, 0, stream,
                       p2, p3, p4, p5, props, outp);
}